// Round 4
// baseline (468.501 us; speedup 1.0000x reference)
//
#include <hip/hip_runtime.h>
#include <hip/hip_bf16.h>

// B=4, N=4096 -> T=16384 tokens, D=1024, H=4096, OUT=1024, 4 nested experts.
#define T_TOK 16384
#define DMODEL 1024
#define HDIM 4096
#define OUTD 1024

typedef __attribute__((ext_vector_type(8))) short short8_t;  // 8 x bf16
typedef __attribute__((ext_vector_type(4))) float f32x4;     // MFMA acc

// ---- ws layout ----
// [0]    counts[4] | [64] hbase[4] | [96] xbase[4] | [128] list[4*16384]
// [1MB]  xc   (compact gathered bf16 x, worst case 32MB)
// [34MB] w1bf (8MB) | [43MB] w2bf (8MB) | [52MB] hbuf (~63MB uniform)
#define WS_COUNTS_OFF 0
#define WS_HBASE_OFF 64
#define WS_XBASE_OFF 96
#define WS_LIST_OFF 128
#define WS_XC_OFF   ((size_t)1 << 20)
#define WS_W1BF_OFF ((size_t)34 << 20)
#define WS_W2BF_OFF ((size_t)43 << 20)
#define WS_HBUF_OFF ((size_t)52 << 20)

#define W1N (HDIM * DMODEL)
#define W2N (OUTD * HDIM)

__device__ __forceinline__ short f2bf(float f) {
    union { float f; unsigned u; } x; x.f = f;
    unsigned r = x.u + 0x7FFFu + ((x.u >> 16) & 1u);  // RNE
    return (short)(r >> 16);
}

__device__ __forceinline__ float gelu_exact(float v) {
    return 0.5f * v * (1.0f + erff(v * 0.7071067811865476f));
}

__device__ __forceinline__ void conv8(const float* __restrict__ s, short* __restrict__ d) {
    const float4* s4 = (const float4*)s;
    float4 f0 = s4[0], f1 = s4[1];
    short8_t v;
    v[0] = f2bf(f0.x); v[1] = f2bf(f0.y); v[2] = f2bf(f0.z); v[3] = f2bf(f0.w);
    v[4] = f2bf(f1.x); v[5] = f2bf(f1.y); v[6] = f2bf(f1.z); v[7] = f2bf(f1.w);
    *(short8_t*)d = v;
}

__device__ __forceinline__ void gl_lds16(const short* g, short* lds) {
    __builtin_amdgcn_global_load_lds(
        (const __attribute__((address_space(1))) void*)g,
        (__attribute__((address_space(3))) void*)lds, 16, 0, 0);
}

// weights only (x handled by k_xgather)
__global__ void k_convert(const float* __restrict__ w1, const float* __restrict__ w2,
                          short* __restrict__ w1bf, short* __restrict__ w2bf) {
    size_t elem = ((size_t)blockIdx.x * blockDim.x + threadIdx.x) * 8;
    if (elem < (size_t)W1N) {
        conv8(w1 + elem, w1bf + elem);
    } else {
        size_t o = elem - W1N; conv8(w2 + o, w2bf + o);
    }
}

__global__ void k_init(int* counts) {
    if (threadIdx.x < 4) counts[threadIdx.x] = 0;
}

// LDS-histogram build: 256 global atomics total
__global__ void k_build(const int* __restrict__ mask, int* counts, int* list) {
    __shared__ int hcnt[4], hb[4], hpos[4];
    int tid = threadIdx.x;
    if (tid < 4) hcnt[tid] = 0;
    __syncthreads();
    int t = blockIdx.x * 256 + tid;
    int e = mask[t] & 3;
    atomicAdd(&hcnt[e], 1);
    __syncthreads();
    if (tid < 4) { hb[tid] = atomicAdd(&counts[tid], hcnt[tid]); hpos[tid] = 0; }
    __syncthreads();
    int p = atomicAdd(&hpos[e], 1);
    list[e * T_TOK + hb[e] + p] = t;
}

__global__ void k_bases(const int* counts, unsigned long long* hbase,
                        unsigned long long* xbase) {
    if (threadIdx.x == 0) {
        unsigned long long ha = 0, xa = 0;
        for (int e = 0; e < 4; ++e) {
            hbase[e] = ha; xbase[e] = xa;
            int d_in = 128 << e;
            ha += (unsigned long long)counts[e] * (unsigned long long)(d_in * 4);
            xa += (unsigned long long)counts[e] * (unsigned long long)d_in;
        }
    }
}

// gather-convert: xc[e][i, :d_in] = bf16(x[list[e][i], :d_in])
__global__ void k_xgather(const float* __restrict__ x, const int* __restrict__ counts,
                          const unsigned long long* __restrict__ xbase,
                          const int* __restrict__ list, short* __restrict__ xc) {
    const int e = blockIdx.y;
    const int d_in = 128 << e;
    const int cnt = counts[e];
    const size_t nel = (size_t)cnt * d_in;
    const int* lst = list + e * T_TOK;
    short* dst = xc + xbase[e];
    for (size_t idx = ((size_t)blockIdx.x * 256 + threadIdx.x) * 8; idx < nel;
         idx += (size_t)gridDim.x * 256 * 8) {
        int row = (int)(idx >> (7 + e));
        int col = (int)(idx & (d_in - 1));
        int tok = lst[row];
        conv8(x + (size_t)tok * DMODEL + col, dst + idx);
    }
}

// ---------------------------------------------------------------------------
// Pass 1: h = gelu(xc @ W1[:d_hid, :d_in]^T + b1)  (bf16, compact rows)
// m97 structure: single 32KB LDS buffer, BK=64, 2 barriers/k-step.
// Up to 5 blocks/CU by LDS; cross-block overlap hides the barrier drain.
// blockIdx.y in [0,60): e0:4, e1:8, e2:16, e3:32 n-tiles of 128.
// ---------------------------------------------------------------------------
__global__ __launch_bounds__(256) void k_pass1(
    const short* __restrict__ xc, const short* __restrict__ w1bf,
    const float* __restrict__ b1,
    const int* __restrict__ counts, const unsigned long long* __restrict__ hbase,
    const unsigned long long* __restrict__ xbase, short* __restrict__ hbuf)
{
    int by = blockIdx.y;
    int e, nt;
    if (by < 4)       { e = 0; nt = by; }
    else if (by < 12) { e = 1; nt = by - 4; }
    else if (by < 28) { e = 2; nt = by - 12; }
    else              { e = 3; nt = by - 28; }
    const int d_in = 128 << e;
    const int d_hid = d_in * 4;
    const int n0 = nt * 128;
    const int cnt = counts[e];
    const unsigned long long hb = hbase[e];
    const short* xe = xc + xbase[e];

    __shared__ short Abuf[128 * 64];   // 16KB
    __shared__ short Bbuf[128 * 64];   // 16KB

    const int tid = threadIdx.x;
    const int lane = tid & 63;
    const int w = tid >> 6;
    const int wm = (w >> 1) * 64;
    const int wn = (w & 1) * 64;
    const int lrow = lane >> 3;
    const int gch = (lane & 7) ^ lrow;     // swizzled source chunk

    for (int m0 = blockIdx.x * 128; m0 < cnt; m0 += 32 * 128) {
        int rowA[4];
#pragma unroll
        for (int j = 0; j < 4; ++j) {
            int rr = m0 + w * 32 + j * 8 + lrow;
            if (rr >= cnt) rr = cnt - 1;
            rowA[j] = rr;
        }

        f32x4 acc[4][4];
#pragma unroll
        for (int i = 0; i < 4; ++i)
#pragma unroll
            for (int j = 0; j < 4; ++j)
                acc[i][j] = (f32x4){0.f, 0.f, 0.f, 0.f};

        for (int k0 = 0; k0 < d_in; k0 += 64) {
#pragma unroll
            for (int j = 0; j < 4; ++j) {
                gl_lds16(xe + (size_t)rowA[j] * d_in + k0 + gch * 8,
                         &Abuf[(w * 32 + j * 8) * 64]);
                gl_lds16(w1bf + (size_t)(n0 + w * 32 + j * 8 + lrow) * DMODEL + k0 + gch * 8,
                         &Bbuf[(w * 32 + j * 8) * 64]);
            }
            __syncthreads();
#pragma unroll
            for (int kk = 0; kk < 2; ++kk) {
                short8_t af[4], bfr[4];
                const int q = (lane >> 4) + kk * 4;
#pragma unroll
                for (int mt = 0; mt < 4; ++mt) {
                    int row = wm + mt * 16 + (lane & 15);
                    af[mt] = *(const short8_t*)&Abuf[((row << 3) | (q ^ (row & 7))) << 3];
                }
#pragma unroll
                for (int ntn = 0; ntn < 4; ++ntn) {
                    int row = wn + ntn * 16 + (lane & 15);
                    bfr[ntn] = *(const short8_t*)&Bbuf[((row << 3) | (q ^ (row & 7))) << 3];
                }
#pragma unroll
                for (int mt = 0; mt < 4; ++mt)
#pragma unroll
                    for (int ntn = 0; ntn < 4; ++ntn)
                        acc[mt][ntn] = __builtin_amdgcn_mfma_f32_16x16x32_bf16(
                            af[mt], bfr[ntn], acc[mt][ntn], 0, 0, 0);
            }
            __syncthreads();
        }

        const int col_l = lane & 15;
        const int qr = lane >> 4;
#pragma unroll
        for (int ntn = 0; ntn < 4; ++ntn) {
            int col = n0 + wn + ntn * 16 + col_l;
            float bias = b1[col];
#pragma unroll
            for (int mt = 0; mt < 4; ++mt) {
#pragma unroll
                for (int r = 0; r < 4; ++r) {
                    int row = wm + mt * 16 + qr * 4 + r;
                    if (m0 + row < cnt) {
                        float v = acc[mt][ntn][r] + bias;
                        hbuf[hb + (unsigned long long)(m0 + row) * d_hid + col] =
                            f2bf(gelu_exact(v));
                    }
                }
            }
        }
    }
}

// ---------------------------------------------------------------------------
// Pass 2: y[tok, :d_out] += h @ W2[:d_out, kh-half]^T (+ b2 on kh==0)
// Split-K x2 for ALL experts -> 960 uniform-ish blocks; fp32 atomicAdd
// epilogue (y pre-zeroed by memset). m97 structure, 32KB LDS.
// blockIdx.y in [0,30): slots per expert = active_ntiles*2 = 2,4,8,16.
// ---------------------------------------------------------------------------
__global__ __launch_bounds__(256) void k_pass2(
    const short* __restrict__ hbuf, const short* __restrict__ w2bf,
    const float* __restrict__ b2,
    const int* __restrict__ counts, const unsigned long long* __restrict__ hbase,
    const int* __restrict__ list, float* __restrict__ y)
{
    int by = blockIdx.y;
    int e, slot;
    if (by < 2)       { e = 0; slot = by; }
    else if (by < 6)  { e = 1; slot = by - 2; }
    else if (by < 14) { e = 2; slot = by - 6; }
    else              { e = 3; slot = by - 14; }
    const int nt = slot >> 1;          // n-tile
    const int kh = slot & 1;           // k-half
    const int d_in = 128 << e;
    const int d_hid = d_in * 4;
    const int khalf = d_hid >> 1;
    const int kbase = kh * khalf;
    const int n0 = nt * 128;
    const int cnt = counts[e];
    const int* lst = list + e * T_TOK;
    const unsigned long long hb = hbase[e];

    __shared__ short Abuf[128 * 64];
    __shared__ short Bbuf[128 * 64];

    const int tid = threadIdx.x;
    const int lane = tid & 63;
    const int w = tid >> 6;
    const int wm = (w >> 1) * 64;
    const int wn = (w & 1) * 64;
    const int lrow = lane >> 3;
    const int gch = (lane & 7) ^ lrow;

    for (int m0 = blockIdx.x * 128; m0 < cnt; m0 += 32 * 128) {
        int rowA[4];
#pragma unroll
        for (int j = 0; j < 4; ++j) {
            int rr = m0 + w * 32 + j * 8 + lrow;
            if (rr >= cnt) rr = cnt - 1;
            rowA[j] = rr;
        }

        f32x4 acc[4][4];
#pragma unroll
        for (int i = 0; i < 4; ++i)
#pragma unroll
            for (int j = 0; j < 4; ++j)
                acc[i][j] = (f32x4){0.f, 0.f, 0.f, 0.f};

        for (int k0 = 0; k0 < khalf; k0 += 64) {
#pragma unroll
            for (int j = 0; j < 4; ++j) {
                gl_lds16(hbuf + hb + (size_t)rowA[j] * d_hid + kbase + k0 + gch * 8,
                         &Abuf[(w * 32 + j * 8) * 64]);
                gl_lds16(w2bf + (size_t)(n0 + w * 32 + j * 8 + lrow) * HDIM + kbase + k0 + gch * 8,
                         &Bbuf[(w * 32 + j * 8) * 64]);
            }
            __syncthreads();
#pragma unroll
            for (int kk = 0; kk < 2; ++kk) {
                short8_t af[4], bfr[4];
                const int q = (lane >> 4) + kk * 4;
#pragma unroll
                for (int mt = 0; mt < 4; ++mt) {
                    int row = wm + mt * 16 + (lane & 15);
                    af[mt] = *(const short8_t*)&Abuf[((row << 3) | (q ^ (row & 7))) << 3];
                }
#pragma unroll
                for (int ntn = 0; ntn < 4; ++ntn) {
                    int row = wn + ntn * 16 + (lane & 15);
                    bfr[ntn] = *(const short8_t*)&Bbuf[((row << 3) | (q ^ (row & 7))) << 3];
                }
#pragma unroll
                for (int mt = 0; mt < 4; ++mt)
#pragma unroll
                    for (int ntn = 0; ntn < 4; ++ntn)
                        acc[mt][ntn] = __builtin_amdgcn_mfma_f32_16x16x32_bf16(
                            af[mt], bfr[ntn], acc[mt][ntn], 0, 0, 0);
            }
            __syncthreads();
        }

        const int col_l = lane & 15;
        const int qr = lane >> 4;
#pragma unroll
        for (int ntn = 0; ntn < 4; ++ntn) {
            int col = n0 + wn + ntn * 16 + col_l;
            float bias = (kh == 0) ? b2[col] : 0.f;
#pragma unroll
            for (int mt = 0; mt < 4; ++mt) {
#pragma unroll
                for (int r = 0; r < 4; ++r) {
                    int row = wm + mt * 16 + qr * 4 + r;
                    if (m0 + row < cnt) {
                        int tok = lst[m0 + row];
                        atomicAdd(&y[(size_t)tok * OUTD + col], acc[mt][ntn][r] + bias);
                    }
                }
            }
        }
    }
}

extern "C" void kernel_launch(void* const* d_in, const int* in_sizes, int n_in,
                              void* d_out, int out_size, void* d_ws, size_t ws_size,
                              hipStream_t stream) {
    const float* x  = (const float*)d_in[0];
    const int* mask = (const int*)d_in[1];
    const float* w1 = (const float*)d_in[2];
    const float* b1 = (const float*)d_in[3];
    const float* w2 = (const float*)d_in[4];
    const float* b2 = (const float*)d_in[5];
    float* y = (float*)d_out;

    char* ws = (char*)d_ws;
    int* counts = (int*)(ws + WS_COUNTS_OFF);
    unsigned long long* hbase = (unsigned long long*)(ws + WS_HBASE_OFF);
    unsigned long long* xbase = (unsigned long long*)(ws + WS_XBASE_OFF);
    int* list = (int*)(ws + WS_LIST_OFF);
    short* xc   = (short*)(ws + WS_XC_OFF);
    short* w1bf = (short*)(ws + WS_W1BF_OFF);
    short* w2bf = (short*)(ws + WS_W2BF_OFF);
    short* hbuf = (short*)(ws + WS_HBUF_OFF);

    // zero y (atomic accumulation base + zero-fill of cols >= d_out)
    hipMemsetAsync(d_out, 0, (size_t)out_size * sizeof(float), stream);

    // weights -> bf16 (8MB+8MB writes)
    k_convert<<<(W1N + W2N) / 8 / 256, 256, 0, stream>>>(w1, w2, w1bf, w2bf);

    k_init<<<1, 64, 0, stream>>>(counts);
    k_build<<<T_TOK / 256, 256, 0, stream>>>(mask, counts, list);
    k_bases<<<1, 1, 0, stream>>>(counts, hbase, xbase);
    k_xgather<<<dim3(128, 4), 256, 0, stream>>>(x, counts, xbase, list, xc);

    k_pass1<<<dim3(32, 60), 256, 0, stream>>>(xc, w1bf, b1, counts, hbase, xbase, hbuf);
    k_pass2<<<dim3(32, 30), 256, 0, stream>>>(hbuf, w2bf, b2, counts, hbase, list, y);
}

// Round 5
// 377.223 us; speedup vs baseline: 1.2420x; 1.2420x over previous
//
#include <hip/hip_runtime.h>
#include <hip/hip_bf16.h>

// B=4, N=4096 -> T=16384 tokens, D=1024, H=4096, OUT=1024, 4 nested experts.
#define T_TOK 16384
#define DMODEL 1024
#define HDIM 4096
#define OUTD 1024

typedef __attribute__((ext_vector_type(8))) short short8_t;  // 8 x bf16
typedef __attribute__((ext_vector_type(4))) float f32x4;     // MFMA acc

// ---- ws layout ----
// [0] counts[4] | [64] hbase[4] | [96] xbase[4] | [128] list[4*16384]
// [1MB] xc (<=32MB) | [34MB] w1bf (8MB) | [43MB] w2bf (8MB) | [52MB] hbuf (~63MB)
#define WS_COUNTS_OFF 0
#define WS_HBASE_OFF 64
#define WS_XBASE_OFF 96
#define WS_LIST_OFF 128
#define WS_XC_OFF   ((size_t)1 << 20)
#define WS_W1BF_OFF ((size_t)34 << 20)
#define WS_W2BF_OFF ((size_t)43 << 20)
#define WS_HBUF_OFF ((size_t)52 << 20)

#define W1N (HDIM * DMODEL)
#define W2N (OUTD * HDIM)

__device__ __forceinline__ short f2bf(float f) {
    union { float f; unsigned u; } x; x.f = f;
    unsigned r = x.u + 0x7FFFu + ((x.u >> 16) & 1u);  // RNE
    return (short)(r >> 16);
}

__device__ __forceinline__ float gelu_exact(float v) {
    return 0.5f * v * (1.0f + erff(v * 0.7071067811865476f));
}

__device__ __forceinline__ void conv8(const float* __restrict__ s, short* __restrict__ d) {
    const float4* s4 = (const float4*)s;
    float4 f0 = s4[0], f1 = s4[1];
    short8_t v;
    v[0] = f2bf(f0.x); v[1] = f2bf(f0.y); v[2] = f2bf(f0.z); v[3] = f2bf(f0.w);
    v[4] = f2bf(f1.x); v[5] = f2bf(f1.y); v[6] = f2bf(f1.z); v[7] = f2bf(f1.w);
    *(short8_t*)d = v;
}

__device__ __forceinline__ void gl_lds16(const short* g, short* lds) {
    __builtin_amdgcn_global_load_lds(
        (const __attribute__((address_space(1))) void*)g,
        (__attribute__((address_space(3))) void*)lds, 16, 0, 0);
}

__global__ void k_convert(const float* __restrict__ w1, const float* __restrict__ w2,
                          short* __restrict__ w1bf, short* __restrict__ w2bf) {
    size_t elem = ((size_t)blockIdx.x * blockDim.x + threadIdx.x) * 8;
    if (elem < (size_t)W1N) {
        conv8(w1 + elem, w1bf + elem);
    } else {
        size_t o = elem - W1N; conv8(w2 + o, w2bf + o);
    }
}

__global__ void k_init(int* counts) {
    if (threadIdx.x < 4) counts[threadIdx.x] = 0;
}

__global__ void k_build(const int* __restrict__ mask, int* counts, int* list) {
    __shared__ int hcnt[4], hb[4], hpos[4];
    int tid = threadIdx.x;
    if (tid < 4) hcnt[tid] = 0;
    __syncthreads();
    int t = blockIdx.x * 256 + tid;
    int e = mask[t] & 3;
    atomicAdd(&hcnt[e], 1);
    __syncthreads();
    if (tid < 4) { hb[tid] = atomicAdd(&counts[tid], hcnt[tid]); hpos[tid] = 0; }
    __syncthreads();
    int p = atomicAdd(&hpos[e], 1);
    list[e * T_TOK + hb[e] + p] = t;
}

__global__ void k_bases(const int* counts, unsigned long long* hbase,
                        unsigned long long* xbase) {
    if (threadIdx.x == 0) {
        unsigned long long ha = 0, xa = 0;
        for (int e = 0; e < 4; ++e) {
            hbase[e] = ha; xbase[e] = xa;
            int d_in = 128 << e;
            ha += (unsigned long long)counts[e] * (unsigned long long)(d_in * 4);
            xa += (unsigned long long)counts[e] * (unsigned long long)d_in;
        }
    }
}

// gather-convert: xc[e][i, :d_in] = bf16(x[list[e][i], :d_in])
__global__ void k_xgather(const float* __restrict__ x, const int* __restrict__ counts,
                          const unsigned long long* __restrict__ xbase,
                          const int* __restrict__ list, short* __restrict__ xc) {
    const int e = blockIdx.y;
    const int d_in = 128 << e;
    const int cnt = counts[e];
    const size_t nel = (size_t)cnt * d_in;
    const int* lst = list + e * T_TOK;
    short* dst = xc + xbase[e];
    for (size_t idx = ((size_t)blockIdx.x * 256 + threadIdx.x) * 8; idx < nel;
         idx += (size_t)gridDim.x * 256 * 8) {
        int row = (int)(idx >> (7 + e));
        int col = (int)(idx & (d_in - 1));
        int tok = lst[row];
        conv8(x + (size_t)tok * DMODEL + col, dst + idx);
    }
}

// ---------------------------------------------------------------------------
// Pass 1: h = gelu(xc @ W1[:d_hid, :d_in]^T + b1)  (bf16, compact rows)
// 64m x 128n tile, BK=64, single 24KB LDS buffer (6 blocks/CU), m97-style
// 2-barrier K-loop. 3840 blocks (15/CU) -> TLP hides DMA latency.
// by order: e3 (longest K) first for LPT scheduling.
// ---------------------------------------------------------------------------
__global__ __launch_bounds__(256) void k_pass1(
    const short* __restrict__ xc, const short* __restrict__ w1bf,
    const float* __restrict__ b1,
    const int* __restrict__ counts, const unsigned long long* __restrict__ hbase,
    const unsigned long long* __restrict__ xbase, short* __restrict__ hbuf)
{
    int by = blockIdx.y;
    int e, nt;
    if (by < 32)      { e = 3; nt = by; }
    else if (by < 48) { e = 2; nt = by - 32; }
    else if (by < 56) { e = 1; nt = by - 48; }
    else              { e = 0; nt = by - 56; }
    const int d_in = 128 << e;
    const int d_hid = d_in * 4;
    const int n0 = nt * 128;
    const int cnt = counts[e];
    const unsigned long long hb = hbase[e];
    const short* xe = xc + xbase[e];

    __shared__ short Ab[64 * 64];    // 8KB
    __shared__ short Bb[128 * 64];   // 16KB

    const int tid = threadIdx.x;
    const int lane = tid & 63;
    const int w = tid >> 6;
    const int l3 = lane >> 3;        // 0..7
    const int ch = lane & 7;
    const int wm = (w & 1) * 32;
    const int wn = (w >> 1) * 64;

    for (int m0 = blockIdx.x * 64; m0 < cnt; m0 += 64 * 64) {
        // A staging rows for this thread's 2 rounds (clamped)
        int rA[2];
#pragma unroll
        for (int j = 0; j < 2; ++j) {
            int rr = m0 + j * 32 + w * 8 + l3;
            rA[j] = (rr >= cnt) ? (cnt - 1) : rr;
        }

        f32x4 acc[2][4];
#pragma unroll
        for (int i = 0; i < 2; ++i)
#pragma unroll
            for (int j = 0; j < 4; ++j)
                acc[i][j] = (f32x4){0.f, 0.f, 0.f, 0.f};

        for (int k0 = 0; k0 < d_in; k0 += 64) {
#pragma unroll
            for (int j = 0; j < 2; ++j) {
                int r = j * 32 + w * 8 + l3;
                gl_lds16(xe + (size_t)rA[j] * d_in + k0 + ((ch ^ (r & 7)) << 3),
                         &Ab[(j * 32 + w * 8) * 64]);
            }
#pragma unroll
            for (int j = 0; j < 4; ++j) {
                int r = j * 32 + w * 8 + l3;
                gl_lds16(w1bf + (size_t)(n0 + r) * DMODEL + k0 + ((ch ^ (r & 7)) << 3),
                         &Bb[(j * 32 + w * 8) * 64]);
            }
            __syncthreads();
#pragma unroll
            for (int kk = 0; kk < 2; ++kk) {
                short8_t af[2], bfr[4];
                const int q = (lane >> 4) + kk * 4;
#pragma unroll
                for (int mt = 0; mt < 2; ++mt) {
                    int row = wm + mt * 16 + (lane & 15);
                    af[mt] = *(const short8_t*)&Ab[((row << 3) | (q ^ (row & 7))) << 3];
                }
#pragma unroll
                for (int ntn = 0; ntn < 4; ++ntn) {
                    int row = wn + ntn * 16 + (lane & 15);
                    bfr[ntn] = *(const short8_t*)&Bb[((row << 3) | (q ^ (row & 7))) << 3];
                }
#pragma unroll
                for (int mt = 0; mt < 2; ++mt)
#pragma unroll
                    for (int ntn = 0; ntn < 4; ++ntn)
                        acc[mt][ntn] = __builtin_amdgcn_mfma_f32_16x16x32_bf16(
                            af[mt], bfr[ntn], acc[mt][ntn], 0, 0, 0);
            }
            __syncthreads();
        }

        const int cl = lane & 15;
        const int qr = lane >> 4;
#pragma unroll
        for (int ntn = 0; ntn < 4; ++ntn) {
            int col = n0 + wn + ntn * 16 + cl;
            float bias = b1[col];
#pragma unroll
            for (int mt = 0; mt < 2; ++mt) {
#pragma unroll
                for (int r = 0; r < 4; ++r) {
                    int row = wm + mt * 16 + qr * 4 + r;
                    if (m0 + row < cnt) {
                        float v = acc[mt][ntn][r] + bias;
                        hbuf[hb + (unsigned long long)(m0 + row) * d_hid + col] =
                            f2bf(gelu_exact(v));
                    }
                }
            }
        }
    }
}

// ---------------------------------------------------------------------------
// Pass 2: y[tok, :d_out] = h @ W2[:d_out, :d_hid]^T + b2  (scatter, fp32)
// 64m x 128n tile, BK=64, double-buffered 48KB LDS (3 blocks/CU), one
// barrier per k-step: DMA(k+1) overlaps compute(k). 960 blocks, e3 first.
// Cols >= d_out are pre-zeroed by memset.
// ---------------------------------------------------------------------------
__global__ __launch_bounds__(256) void k_pass2(
    const short* __restrict__ hbuf, const short* __restrict__ w2bf,
    const float* __restrict__ b2,
    const int* __restrict__ counts, const unsigned long long* __restrict__ hbase,
    const int* __restrict__ list, float* __restrict__ y)
{
    int by = blockIdx.y;
    int e, nt;
    if (by < 8)       { e = 3; nt = by; }
    else if (by < 12) { e = 2; nt = by - 8; }
    else if (by < 14) { e = 1; nt = by - 12; }
    else              { e = 0; nt = 0; }
    const int d_in = 128 << e;
    const int d_hid = d_in * 4;
    const int n0 = nt * 128;
    const int cnt = counts[e];
    const int* lst = list + e * T_TOK;
    const unsigned long long hb = hbase[e];

    __shared__ short Ab[2 * 64 * 64];    // 16KB
    __shared__ short Bb[2 * 128 * 64];   // 32KB

    const int tid = threadIdx.x;
    const int lane = tid & 63;
    const int w = tid >> 6;
    const int l3 = lane >> 3;
    const int ch = lane & 7;
    const int wm = (w & 1) * 32;
    const int wn = (w >> 1) * 64;

    for (int m0 = blockIdx.x * 64; m0 < cnt; m0 += 64 * 64) {
        int rA[2];
#pragma unroll
        for (int j = 0; j < 2; ++j) {
            int rr = m0 + j * 32 + w * 8 + l3;
            rA[j] = (rr >= cnt) ? (cnt - 1) : rr;
        }

        f32x4 acc[2][4];
#pragma unroll
        for (int i = 0; i < 2; ++i)
#pragma unroll
            for (int j = 0; j < 4; ++j)
                acc[i][j] = (f32x4){0.f, 0.f, 0.f, 0.f};

        const int ks = d_hid >> 6;
        // prologue: stage kt=0 into buffer 0
#pragma unroll
        for (int j = 0; j < 2; ++j) {
            int r = j * 32 + w * 8 + l3;
            gl_lds16(hbuf + hb + (size_t)rA[j] * d_hid + ((ch ^ (r & 7)) << 3),
                     &Ab[(j * 32 + w * 8) * 64]);
        }
#pragma unroll
        for (int j = 0; j < 4; ++j) {
            int r = j * 32 + w * 8 + l3;
            gl_lds16(w2bf + (size_t)(n0 + r) * HDIM + ((ch ^ (r & 7)) << 3),
                     &Bb[(j * 32 + w * 8) * 64]);
        }
        for (int kt = 0; kt < ks; ++kt) {
            const int p = kt & 1;
            __syncthreads();   // drains buf[p] DMA; guards buf[1-p] reuse
            if (kt + 1 < ks) {
                const int kn = (kt + 1) << 6;
                const int qb = 1 - p;
#pragma unroll
                for (int j = 0; j < 2; ++j) {
                    int r = j * 32 + w * 8 + l3;
                    gl_lds16(hbuf + hb + (size_t)rA[j] * d_hid + kn + ((ch ^ (r & 7)) << 3),
                             &Ab[(qb * 4096) + (j * 32 + w * 8) * 64]);
                }
#pragma unroll
                for (int j = 0; j < 4; ++j) {
                    int r = j * 32 + w * 8 + l3;
                    gl_lds16(w2bf + (size_t)(n0 + r) * HDIM + kn + ((ch ^ (r & 7)) << 3),
                             &Bb[(qb * 8192) + (j * 32 + w * 8) * 64]);
                }
            }
            const short* Ap = &Ab[p * 4096];
            const short* Bp = &Bb[p * 8192];
#pragma unroll
            for (int kk = 0; kk < 2; ++kk) {
                short8_t af[2], bfr[4];
                const int q = (lane >> 4) + kk * 4;
#pragma unroll
                for (int mt = 0; mt < 2; ++mt) {
                    int row = wm + mt * 16 + (lane & 15);
                    af[mt] = *(const short8_t*)&Ap[((row << 3) | (q ^ (row & 7))) << 3];
                }
#pragma unroll
                for (int ntn = 0; ntn < 4; ++ntn) {
                    int row = wn + ntn * 16 + (lane & 15);
                    bfr[ntn] = *(const short8_t*)&Bp[((row << 3) | (q ^ (row & 7))) << 3];
                }
#pragma unroll
                for (int mt = 0; mt < 2; ++mt)
#pragma unroll
                    for (int ntn = 0; ntn < 4; ++ntn)
                        acc[mt][ntn] = __builtin_amdgcn_mfma_f32_16x16x32_bf16(
                            af[mt], bfr[ntn], acc[mt][ntn], 0, 0, 0);
            }
        }
        __syncthreads();  // all buffer reads done before next m-iter stages

        const int cl = lane & 15;
        const int qr = lane >> 4;
#pragma unroll
        for (int ntn = 0; ntn < 4; ++ntn) {
            int col = n0 + wn + ntn * 16 + cl;
            float bias = b2[col];
#pragma unroll
            for (int mt = 0; mt < 2; ++mt) {
#pragma unroll
                for (int r = 0; r < 4; ++r) {
                    int row = wm + mt * 16 + qr * 4 + r;
                    if (m0 + row < cnt) {
                        int tok = lst[m0 + row];
                        y[(size_t)tok * OUTD + col] = acc[mt][ntn][r] + bias;
                    }
                }
            }
        }
    }
}

extern "C" void kernel_launch(void* const* d_in, const int* in_sizes, int n_in,
                              void* d_out, int out_size, void* d_ws, size_t ws_size,
                              hipStream_t stream) {
    const float* x  = (const float*)d_in[0];
    const int* mask = (const int*)d_in[1];
    const float* w1 = (const float*)d_in[2];
    const float* b1 = (const float*)d_in[3];
    const float* w2 = (const float*)d_in[4];
    const float* b2 = (const float*)d_in[5];
    float* y = (float*)d_out;

    char* ws = (char*)d_ws;
    int* counts = (int*)(ws + WS_COUNTS_OFF);
    unsigned long long* hbase = (unsigned long long*)(ws + WS_HBASE_OFF);
    unsigned long long* xbase = (unsigned long long*)(ws + WS_XBASE_OFF);
    int* list = (int*)(ws + WS_LIST_OFF);
    short* xc   = (short*)(ws + WS_XC_OFF);
    short* w1bf = (short*)(ws + WS_W1BF_OFF);
    short* w2bf = (short*)(ws + WS_W2BF_OFF);
    short* hbuf = (short*)(ws + WS_HBUF_OFF);

    // zero y (covers cols >= d_out per token)
    hipMemsetAsync(d_out, 0, (size_t)out_size * sizeof(float), stream);

    k_convert<<<(W1N + W2N) / 8 / 256, 256, 0, stream>>>(w1, w2, w1bf, w2bf);

    k_init<<<1, 64, 0, stream>>>(counts);
    k_build<<<T_TOK / 256, 256, 0, stream>>>(mask, counts, list);
    k_bases<<<1, 1, 0, stream>>>(counts, hbase, xbase);
    k_xgather<<<dim3(128, 4), 256, 0, stream>>>(x, counts, xbase, list, xc);

    k_pass1<<<dim3(64, 60), 256, 0, stream>>>(xc, w1bf, b1, counts, hbase, xbase, hbuf);
    k_pass2<<<dim3(64, 15), 256, 0, stream>>>(hbuf, w2bf, b2, counts, hbase, list, y);
}